// Round 10
// baseline (312.126 us; speedup 1.0000x reference)
//
#include <hip/hip_runtime.h>
#include <hip/hip_bf16.h>
#include <math.h>

typedef float f32x4 __attribute__((ext_vector_type(4)));
typedef int   i32x4 __attribute__((ext_vector_type(4)));
typedef short s16x8 __attribute__((ext_vector_type(8)));

#define NB 4
#define NC 512
#define NM 4096
#define NHEADS 8

// async global->LDS, 16B per lane, LDS dest = wave-uniform base + lane*16
#define GLDS16(src, dst) __builtin_amdgcn_global_load_lds( \
    (const __attribute__((address_space(1))) void*)(src),  \
    (__attribute__((address_space(3))) void*)(dst), 16, 0, 0)

// counted vmcnt waits (exact counts; in-order retirement per ISA/m135)
#define WAITVM0 asm volatile("s_waitcnt vmcnt(0)" ::: "memory")
#define WAITVM2 asm volatile("s_waitcnt vmcnt(2)" ::: "memory")
#define WAITVM6 asm volatile("s_waitcnt vmcnt(6)" ::: "memory")

// ---------------- merged prep + transpose (disjoint outputs, one launch) ----------------
__global__ __launch_bounds__(256) void prep_tr(
    const float* __restrict__ wdw, const float* __restrict__ wkv,
    const float* __restrict__ wq,
    const float* __restrict__ x, const float* __restrict__ y,
    __hip_bfloat16* __restrict__ Wr, __hip_bfloat16* __restrict__ wkvB,
    __hip_bfloat16* __restrict__ wqT, __hip_bfloat16* __restrict__ zeropad,
    float* __restrict__ norms,
    __hip_bfloat16* __restrict__ xT, __hip_bfloat16* __restrict__ yT)
{
  __shared__ __hip_bfloat16 tile[64][68];
  const int bx = blockIdx.x;
  if (bx < 4113) {
    long idx = (long)bx * 256 + threadIdx.x;
    if (idx < 262144) {                        // 512*512 (o,i) pairs, 9 taps each
      const float* s = wdw + idx * 9;
      #pragma unroll
      for (int r = 0; r < 9; r++)
        Wr[(long)r * 262144 + idx] = __float2bfloat16(s[r]);
    } else if (idx < 786432) {                 // + 1024*512
      long j = idx - 262144;
      wkvB[j] = __float2bfloat16(wkv[j]);
    } else if (idx < 1048576) {                // + 512*512
      long j = idx - 786432;
      int c = (int)(j >> 9), cp = (int)(j & 511);
      wqT[j] = __float2bfloat16(wq[(long)cp * 512 + c]);
    } else if (idx < 1048704) {
      zeropad[idx - 1048576] = __float2bfloat16(0.f);
    } else if (idx < 1052800) {
      norms[idx - 1048704] = 0.f;
    }
  } else {
    const int rem = bx - 4113;
    const int z = rem >> 9;                   // 0..3 x batches, 4..7 y batches
    const int tm = (rem & 63) * 64, tc = ((rem >> 6) & 7) * 64;
    const float* src = ((z < 4) ? x : y) + (long)(z & 3) * ((long)NC * NM);
    __hip_bfloat16* dst = (z < 4 ? xT : yT) + (long)(z & 3) * ((long)NC * NM);
    int tx4 = threadIdx.x & 15, trow = threadIdx.x >> 4;
    #pragma unroll
    for (int p = 0; p < 4; p++) {
      int crow = trow + p * 16;
      f32x4 v = *(const f32x4*)&src[(long)(tc + crow) * NM + tm + tx4 * 4];
      #pragma unroll
      for (int t = 0; t < 4; t++) tile[crow][tx4 * 4 + t] = __float2bfloat16(v[t]);
    }
    __syncthreads();
    #pragma unroll
    for (int p = 0; p < 4; p++) {
      int mrow = trow + p * 16;
      union { ushort4 u4; unsigned short u[4]; } o;
      #pragma unroll
      for (int t = 0; t < 4; t++)
        o.u[t] = *(const unsigned short*)&tile[tx4 * 4 + t][mrow];
      *(ushort4*)&dst[(long)(tm + mrow) * NC + tc + tx4 * 4] = o.u4;
    }
  }
}

// ---------------- generic GEMM: C[M,N] = A[M,K] * B[N,K]^T (row-major bf16, fp32 acc) ----------------
// outMode: 0 = bf16 row-major; 1 = f32 row-major; 2 = bf16 MFMA-fragment-packed
__global__ __launch_bounds__(256) void gemm_bt(
    const __hip_bfloat16* __restrict__ Aall, long sA,
    const __hip_bfloat16* __restrict__ Ball, long sB,
    __hip_bfloat16* __restrict__ Cball, float* __restrict__ Cfall, long sC,
    int M, int N, int Kd, int outMode)
{
  const __hip_bfloat16* A = Aall + (long)blockIdx.z * sA;
  const __hip_bfloat16* B = Ball + (long)blockIdx.z * sB;
  const int m0 = blockIdx.y * 128, n0 = blockIdx.x * 128;
  __shared__ __hip_bfloat16 As[128 * 32];
  __shared__ __hip_bfloat16 Bs[128 * 32];
  const int tid = threadIdx.x;
  const int wid = tid >> 6, lane = tid & 63;
  const int wm = (wid >> 1) * 64, wn = (wid & 1) * 64;
  const int quad = lane >> 4, l16 = lane & 15;
  const int srow = wid * 32 + (lane >> 2);
  const int scol = (lane & 3) * 8;
  f32x4 acc[4][4] = {};
  for (int k0 = 0; k0 < Kd; k0 += 32) {
    __syncthreads();
    #pragma unroll
    for (int t = 0; t < 2; t++) {
      GLDS16(A + (long)(m0 + srow + t * 16) * Kd + k0 + scol,
             As + (wid * 32 + t * 16) * 32);
      GLDS16(B + (long)(n0 + srow + t * 16) * Kd + k0 + scol,
             Bs + (wid * 32 + t * 16) * 32);
    }
    __builtin_amdgcn_s_waitcnt(0);
    __syncthreads();
    s16x8 bfr[4];
    #pragma unroll
    for (int j = 0; j < 4; j++)
      bfr[j] = *(const s16x8*)(&Bs[(wn + j * 16 + l16) * 32 + quad * 8]);
    #pragma unroll
    for (int i = 0; i < 4; i++) {
      s16x8 af = *(const s16x8*)(&As[(wm + i * 16 + l16) * 32 + quad * 8]);
      #pragma unroll
      for (int j = 0; j < 4; j++)
        acc[i][j] = __builtin_amdgcn_mfma_f32_16x16x32_bf16(af, bfr[j], acc[i][j], 0, 0, 0);
    }
  }
  if (outMode == 1) {
    float* C = Cfall + (long)blockIdx.z * sC;
    #pragma unroll
    for (int i = 0; i < 4; i++)
      #pragma unroll
      for (int j = 0; j < 4; j++) {
        int rbase = m0 + wm + i * 16 + quad * 4;
        int col = n0 + wn + j * 16 + l16;
        #pragma unroll
        for (int r = 0; r < 4; r++)
          C[(long)(rbase + r) * N + col] = acc[i][j][r];
      }
  } else if (outMode == 2) {
    __hip_bfloat16* C = Cball;          // packed; z-term folded into index
    const int rt = blockIdx.z;          // tap
    #pragma unroll
    for (int i = 0; i < 4; i++)
      #pragma unroll
      for (int j = 0; j < 4; j++) {
        int obase = m0 + wm + i * 16 + quad * 4;
        int col = n0 + wn + j * 16 + l16;
        #pragma unroll
        for (int r = 0; r < 4; r++) {
          int o = obase + r;
          long idx = ((((long)(rt * 32 + (o >> 4)) * 16 + (col >> 5)) << 9)
                      + ((col >> 3) & 3) * 128 + (o & 15) * 8 + (col & 7));
          C[idx] = __float2bfloat16(acc[i][j][r]);
        }
      }
  } else {
    __hip_bfloat16* C = Cball + (long)blockIdx.z * sC;
    #pragma unroll
    for (int i = 0; i < 4; i++)
      #pragma unroll
      for (int j = 0; j < 4; j++) {
        int rbase = m0 + wm + i * 16 + quad * 4;
        int col = n0 + wn + j * 16 + l16;
        #pragma unroll
        for (int r = 0; r < 4; r++)
          C[(long)(rbase + r) * N + col] = __float2bfloat16(acc[i][j][r]);
      }
  }
}

// ---------------- merged K/V GEMM, one launch (z<4: K c-major + knorm2; z>=4: V m-major) ----------------
__global__ __launch_bounds__(256) void gemm_kv(
    const __hip_bfloat16* __restrict__ wkvB,
    const __hip_bfloat16* __restrict__ xT,
    __hip_bfloat16* __restrict__ Kb,
    __hip_bfloat16* __restrict__ Vt,
    float* __restrict__ knorm2)
{
  const int z = blockIdx.z;
  const int b = z & 3;
  const bool kmode = (z < 4);
  const long S = (long)NM * NC;
  const __hip_bfloat16* A = kmode ? wkvB : (xT + b * S);
  const __hip_bfloat16* B = kmode ? (xT + b * S) : (wkvB + 262144);
  __hip_bfloat16* C = kmode ? (Kb + b * S) : (Vt + b * S);
  const int m0 = (kmode ? blockIdx.y : blockIdx.x) * 128;
  const int n0 = (kmode ? blockIdx.x : blockIdx.y) * 128;
  const int N = kmode ? NM : NC;
  __shared__ __hip_bfloat16 As[128 * 32];
  __shared__ __hip_bfloat16 Bs[128 * 32];
  const int tid = threadIdx.x;
  const int wid = tid >> 6, lane = tid & 63;
  const int wm = (wid >> 1) * 64, wn = (wid & 1) * 64;
  const int quad = lane >> 4, l16 = lane & 15;
  const int srow = wid * 32 + (lane >> 2);
  const int scol = (lane & 3) * 8;
  f32x4 acc[4][4] = {};
  for (int k0 = 0; k0 < NC; k0 += 32) {
    __syncthreads();
    #pragma unroll
    for (int t = 0; t < 2; t++) {
      GLDS16(A + (long)(m0 + srow + t * 16) * NC + k0 + scol,
             As + (wid * 32 + t * 16) * 32);
      GLDS16(B + (long)(n0 + srow + t * 16) * NC + k0 + scol,
             Bs + (wid * 32 + t * 16) * 32);
    }
    __builtin_amdgcn_s_waitcnt(0);
    __syncthreads();
    s16x8 bfr[4];
    #pragma unroll
    for (int j = 0; j < 4; j++)
      bfr[j] = *(const s16x8*)(&Bs[(wn + j * 16 + l16) * 32 + quad * 8]);
    #pragma unroll
    for (int i = 0; i < 4; i++) {
      s16x8 af = *(const s16x8*)(&As[(wm + i * 16 + l16) * 32 + quad * 8]);
      #pragma unroll
      for (int j = 0; j < 4; j++)
        acc[i][j] = __builtin_amdgcn_mfma_f32_16x16x32_bf16(af, bfr[j], acc[i][j], 0, 0, 0);
    }
  }
  #pragma unroll
  for (int i = 0; i < 4; i++)
    #pragma unroll
    for (int j = 0; j < 4; j++) {
      int rbase = m0 + wm + i * 16 + quad * 4;
      int col = n0 + wn + j * 16 + l16;
      #pragma unroll
      for (int r = 0; r < 4; r++)
        C[(long)(rbase + r) * N + col] = __float2bfloat16(acc[i][j][r]);
    }
  if (kmode) {     // knorm2[b*512 + c] += sum over this tile's m-cols of K[c,m]^2
    #pragma unroll
    for (int i = 0; i < 4; i++) {
      int rbase = m0 + wm + i * 16 + quad * 4;
      #pragma unroll
      for (int r = 0; r < 4; r++) {
        float s = 0.f;
        #pragma unroll
        for (int j = 0; j < 4; j++) s += acc[i][j][r] * acc[i][j][r];
        s += __shfl_xor(s, 1); s += __shfl_xor(s, 2);
        s += __shfl_xor(s, 4); s += __shfl_xor(s, 8);
        if (l16 == 0) atomicAdd(&knorm2[b * 512 + rbase + r], s);
      }
    }
  }
}

// ---------------- 3x3 conv as implicit GEMM (w_q folded), + qnorm2 partials ----------------
// v10: T3+T4 counted-vmcnt schedule. A staged in a 3-slot ring of 8KB tap-buffers
//      (stream of 144 taps; slot = tap%3, 2-tap prefetch distance). Per tap:
//      exact counted s_waitcnt vmcnt(2|6) -> raw s_barrier (no compiler drain) ->
//      issue tap+2 DMA (+ next-icb B at tap 4) -> 16 MFMA. ZERO vmcnt(0) drains in
//      the main loop (v9 had 48). Counts are exact under in-order vmcnt retirement:
//      2 = next tap's A-pair; 6 = +B-quad in the two taps after a B issue.
//      B staging + swizzle unchanged (proven). LDS 56KB -> 2 blocks/CU.
__global__ __launch_bounds__(256) void conv3x3(
    const __hip_bfloat16* __restrict__ Wp,   // packed [9][32][16][64][8] fragments
    const __hip_bfloat16* __restrict__ yT,   // [b][4096][512]
    const __hip_bfloat16* __restrict__ zeropad,
    __hip_bfloat16* __restrict__ q2,         // [b][512][4096]
    float* __restrict__ qnorm2)
{
  const int b = blockIdx.z;
  const int n0 = blockIdx.x * 128;   // hw tile (2 image rows)
  const int m0 = blockIdx.y * 128;   // o tile
  __shared__ __hip_bfloat16 As3[3][8 * 512];    // 3 x 8KB ring: one tap (8 packed frags)
  __shared__ __hip_bfloat16 Bs2[2][256 * 32];   // 2 x 16KB: 4 image rows (incl halo) x 32 ic
  const int tid = threadIdx.x;
  const int wid = tid >> 6, lane = tid & 63;
  const int wm = (wid >> 1) * 64, wn = (wid & 1) * 64;
  const int quad = lane >> 4, l16 = lane & 15;
  const int lrow = lane >> 2;
  const int h0 = n0 >> 6;
  const int mb0b = m0 >> 4;
  const int mwl = wm >> 4;            // 0 or 4: this wave's mb offset within block
  const __hip_bfloat16* yb = yT + (long)b * NM * NC;
  f32x4 acc[4][4] = {};
  const s16x8 zero8 = {0, 0, 0, 0, 0, 0, 0, 0};

  // B staging source column swizzle: slot' = (lane&3) ^ ((lds_row>>1)&3)
  const int sq = ((lane & 3) ^ ((lane >> 3) & 3)) * 8;

  // B LDS read addrs (dy=-1 base; +g*2048 per dy) and validity bits (verified v2-v9).
  int addr0[3][4];
  unsigned vbits = 0;
  #pragma unroll
  for (int t = 0; t < 3; t++) {
    #pragma unroll
    for (int j = 0; j < 4; j++) {
      int nl = wn + j * 16 + l16;
      int wq_ = nl & 63, hr = nl >> 6;
      int wp = wq_ + t - 1;                  // dx = t-1
      unsigned v = ((unsigned)wp) < 64u;
      int p = v ? (hr * 64 + wp) : 0;        // dy=-1: row hr
      addr0[t][j] = p * 32 + ((quad ^ ((p >> 1) & 3)) * 8);
      vbits |= v << (t * 4 + j);
    }
  }

  // per-wave A frag pair within each tap (8 frags / 4 waves)
  const int f0 = wid * 2, f1 = wid * 2 + 1;

#define AISSUE(slot_, rt_, icb_) { \
    GLDS16(Wp + (((long)((rt_) * 32 + mb0b + f0) * 16 + (icb_)) << 9) + lane * 8, \
           &As3[slot_][f0 * 512]); \
    GLDS16(Wp + (((long)((rt_) * 32 + mb0b + f1) * 16 + (icb_)) << 9) + lane * 8, \
           &As3[slot_][f1 * 512]); }

#define BISSUE(icb_, bufidx_) { \
    _Pragma("unroll") \
    for (int t_ = 0; t_ < 4; t_++) { \
      int pr = wid * 64 + t_ * 16 + lrow; \
      int hw = (h0 - 1) * 64 + pr; \
      const __hip_bfloat16* src = (((unsigned)hw) < (unsigned)NM) \
          ? (yb + (long)hw * NC + (icb_) * 32 + sq) : zeropad; \
      GLDS16(src, &Bs2[bufidx_][(wid * 64 + t_ * 16) * 32]); \
    } }

  // prologue (issue order matters for in-order vmcnt): B(icb0) FIRST, then A(tap0), A(tap1)
  BISSUE(0, 0);
  AISSUE(0, 0, 0);
  AISSUE(1, 1, 0);

  for (int icb = 0; icb < 16; icb++) {
    const __hip_bfloat16* Bcur = &Bs2[icb & 1][0];
    #pragma unroll
    for (int tap = 0; tap < 9; tap++) {
      // 1) exact counted wait: own loads for THIS tap retired.
      //    outstanding-after = next tap's A-pair (2), +4 for the B-quad issued at
      //    tap 4 of this icb (visible at taps 5,6), 0 at the final tap of all.
      if (tap == 5 || tap == 6) {
        if (icb < 15) { WAITVM6; } else { WAITVM2; }
      } else if (tap == 8) {
        if (icb == 15) { WAITVM0; } else { WAITVM2; }
      } else {
        WAITVM2;
      }
      // 2) raw barrier: all waves' tap loads landed; all waves done reading tap-1's slot
      asm volatile("" ::: "memory");
      __builtin_amdgcn_s_barrier();
      asm volatile("" ::: "memory");
      // 3) issue tap+2's A into slot (tap+2)%3 (= slot last read at tap-1); B at tap 4
      if (icb < 15 || tap < 7) {
        const int rt2 = (tap + 2) % 9;         // static per unrolled tap
        const int sl2 = (tap + 2) % 3;
        const int icb2 = icb + ((tap + 2) / 9);
        AISSUE(sl2, rt2, icb2);
      }
      if (tap == 4 && icb < 15) BISSUE(icb + 1, (icb & 1) ^ 1);
      // 4) compute this tap: 16 MFMA (g = tap/3, t = tap%3, all static)
      {
        const int g = tap / 3, t = tap % 3;
        s16x8 bfr[4];
        #pragma unroll
        for (int j = 0; j < 4; j++) {
          s16x8 tt = *(const s16x8*)(&Bcur[addr0[t][j] + g * 2048]);
          bfr[j] = ((vbits >> (t * 4 + j)) & 1u) ? tt : zero8;
        }
        #pragma unroll
        for (int i = 0; i < 4; i++) {
          s16x8 af = *(const s16x8*)(&As3[tap % 3][(mwl + i) * 512 + lane * 8]);
          #pragma unroll
          for (int j = 0; j < 4; j++)
            acc[i][j] = __builtin_amdgcn_mfma_f32_16x16x32_bf16(af, bfr[j], acc[i][j], 0, 0, 0);
        }
      }
    }
  }
#undef AISSUE
#undef BISSUE

  __hip_bfloat16* Cb = q2 + (long)b * NC * NM;
  #pragma unroll
  for (int i = 0; i < 4; i++)
    #pragma unroll
    for (int j = 0; j < 4; j++) {
      int rbase = m0 + wm + i * 16 + quad * 4;
      int col = n0 + wn + j * 16 + l16;
      #pragma unroll
      for (int r = 0; r < 4; r++)
        Cb[(long)(rbase + r) * NM + col] = __float2bfloat16(acc[i][j][r]);
    }
  // qnorm2[b*512 + o] += sum over this tile's hw-cols of q2[o,hw]^2
  #pragma unroll
  for (int i = 0; i < 4; i++) {
    int rbase = m0 + wm + i * 16 + quad * 4;
    #pragma unroll
    for (int r = 0; r < 4; r++) {
      float s = 0.f;
      #pragma unroll
      for (int j = 0; j < 4; j++) s += acc[i][j][r] * acc[i][j][r];
      s += __shfl_xor(s, 1); s += __shfl_xor(s, 2);
      s += __shfl_xor(s, 4); s += __shfl_xor(s, 8);
      if (l16 == 0) atomicAdd(&qnorm2[b * 512 + rbase + r], s);
    }
  }
}

// ---------------- attention logits partial: Gpart[b,h,mc][c][d] over m-chunk ----------------
__global__ __launch_bounds__(256) void attn_g(
    const __hip_bfloat16* __restrict__ q2, const __hip_bfloat16* __restrict__ Kb,
    float* __restrict__ Gpart)
{
  const int mc = blockIdx.x, h = blockIdx.y, b = blockIdx.z;
  const __hip_bfloat16* qrow = q2 + ((long)b * NC + h * 64) * NM + mc * 512;
  const __hip_bfloat16* krow = Kb + ((long)b * NC + h * 64) * NM + mc * 512;
  __shared__ __hip_bfloat16 Qs[64 * 40];
  __shared__ __hip_bfloat16 Ks[64 * 40];
  const int tid = threadIdx.x;
  const int wid = tid >> 6, lane = tid & 63;
  const int wc = (wid >> 1) * 32, wd = (wid & 1) * 32;
  const int quad = lane >> 4, l16 = lane & 15;
  const int srow = tid >> 2, scol = (tid & 3) * 8;
  f32x4 acc[2][2] = {};
  for (int k0 = 0; k0 < 512; k0 += 32) {
    __syncthreads();
    *(i32x4*)(&Qs[srow * 40 + scol]) = *(const i32x4*)(&qrow[(long)srow * NM + k0 + scol]);
    *(i32x4*)(&Ks[srow * 40 + scol]) = *(const i32x4*)(&krow[(long)srow * NM + k0 + scol]);
    __syncthreads();
    s16x8 bfr[2];
    #pragma unroll
    for (int j = 0; j < 2; j++)
      bfr[j] = *(const s16x8*)(&Ks[(wd + j * 16 + l16) * 40 + quad * 8]);
    #pragma unroll
    for (int i = 0; i < 2; i++) {
      s16x8 af = *(const s16x8*)(&Qs[(wc + i * 16 + l16) * 40 + quad * 8]);
      #pragma unroll
      for (int j = 0; j < 2; j++)
        acc[i][j] = __builtin_amdgcn_mfma_f32_16x16x32_bf16(af, bfr[j], acc[i][j], 0, 0, 0);
    }
  }
  float* gp = Gpart + ((long)((b * 8 + h) * 8 + mc)) * 4096;
  #pragma unroll
  for (int i = 0; i < 2; i++)
    #pragma unroll
    for (int j = 0; j < 2; j++)
      #pragma unroll
      for (int r = 0; r < 4; r++)
        gp[(wc + i * 16 + quad * 4 + r) * 64 + wd + j * 16 + l16] = acc[i][j][r];
}

// ---------------- fused: sum partials -> normalize -> softmax -> Wa = (wout chunk) . attn ----------------
__global__ __launch_bounds__(256) void softmax_wa(
    const float* __restrict__ Gpart, const float* __restrict__ qnorm2,
    const float* __restrict__ knorm2, const float* __restrict__ temp,
    const float* __restrict__ wout, __hip_bfloat16* __restrict__ Wa)
{
  const int oc = blockIdx.x, h = blockIdx.y, b = blockIdx.z;
  __shared__ float G[64][64];
  __shared__ float Wt[64][65];
  const int tid = threadIdx.x;
  const float tv = temp[h];
  for (int e = tid; e < 4096; e += 256) {
    float s = 0.f;
    #pragma unroll
    for (int p = 0; p < 8; p++)
      s += Gpart[((long)((b * 8 + h) * 8 + p)) * 4096 + e];
    int c = e >> 6, d = e & 63;
    float qn = fmaxf(sqrtf(qnorm2[b * 512 + h * 64 + c]), 1e-12f);
    float kn = fmaxf(sqrtf(knorm2[b * 512 + h * 64 + d]), 1e-12f);
    G[c][d] = s * tv / (qn * kn);
    Wt[c][d] = wout[(long)(oc * 64 + c) * 512 + h * 64 + d];
  }
  __syncthreads();
  int row = tid >> 2, s4 = tid & 3;
  float mx = -1e30f;
  for (int d = s4; d < 64; d += 4) mx = fmaxf(mx, G[row][d]);
  mx = fmaxf(mx, __shfl_xor(mx, 1));
  mx = fmaxf(mx, __shfl_xor(mx, 2));
  float sum = 0.f;
  for (int d = s4; d < 64; d += 4) { float e = __expf(G[row][d] - mx); G[row][d] = e; sum += e; }
  sum += __shfl_xor(sum, 1);
  sum += __shfl_xor(sum, 2);
  float inv = 1.f / sum;
  for (int d = s4; d < 64; d += 4) G[row][d] *= inv;
  __syncthreads();
  int d = tid & 63, og = tid >> 6;
  #pragma unroll
  for (int k2 = 0; k2 < 16; k2++) {
    int o = og * 16 + k2;
    float s = 0.f;
    #pragma unroll 8
    for (int c = 0; c < 64; c++) s += Wt[o][c] * G[c][d];
    Wa[((long)b * 512 + oc * 64 + o) * 512 + h * 64 + d] = __float2bfloat16(s);
  }
}

extern "C" void kernel_launch(void* const* d_in, const int* in_sizes, int n_in,
                              void* d_out, int out_size, void* d_ws, size_t ws_size,
                              hipStream_t stream) {
  const float* x    = (const float*)d_in[0];
  const float* y    = (const float*)d_in[1];
  const float* temp = (const float*)d_in[2];
  const float* wkv  = (const float*)d_in[3];
  const float* wq   = (const float*)d_in[4];
  const float* wdw  = (const float*)d_in[5];
  const float* wout = (const float*)d_in[6];
  float* out = (float*)d_out;     // fp32 output

  char* ws = (char*)d_ws;
  const long TEN = 16777216;  // one (4,512,4096) bf16 tensor, bytes
  __hip_bfloat16* xT  = (__hip_bfloat16*)(ws);               // reused as q2 after kv GEMM
  __hip_bfloat16* q2  = xT;
  __hip_bfloat16* yT  = (__hip_bfloat16*)(ws + TEN);         // reused after conv:
  float* Gpart        = (float*)(ws + TEN);                  //   4 MB
  __hip_bfloat16* Wa  = (__hip_bfloat16*)(ws + TEN + 4718592);   // 2 MB
  __hip_bfloat16* Kb  = (__hip_bfloat16*)(ws + 2 * TEN);
  __hip_bfloat16* Vt  = (__hip_bfloat16*)(ws + 3 * TEN);
  __hip_bfloat16* Wfold = (__hip_bfloat16*)(ws + 4 * TEN);               // 4.72 MB (packed)
  __hip_bfloat16* Wr    = (__hip_bfloat16*)(ws + 4 * TEN + 4718592);     // 4.72 MB
  __hip_bfloat16* wkvB  = (__hip_bfloat16*)(ws + 4 * TEN + 9437184);     // 1 MB
  __hip_bfloat16* wqT   = (__hip_bfloat16*)(ws + 4 * TEN + 10485760);    // 512 KB
  __hip_bfloat16* zeropad = (__hip_bfloat16*)(ws + 4 * TEN + 11010048);  // 256 B
  float* norms          = (float*)(ws + 4 * TEN + 11010304);             // 16 KB
  float* knorm2 = norms;
  float* qnorm2 = norms + 2048;

  const long S = (long)4096 * 512;
  const long S2 = (long)512 * 512;
  dim3 blk(256);

  // merged prep + transpose (4113 prep blocks + 4096 transpose blocks)
  prep_tr<<<dim3(8209), blk, 0, stream>>>(wdw, wkv, wq, x, y,
                                          Wr, wkvB, wqT, zeropad, norms, xT, yT);
  // Wfold (packed fragments): per-tap  fold = Wr[r] . wqT^T, written in conv A-frag order
  gemm_bt<<<dim3(4, 4, 9), blk, 0, stream>>>(Wr, S2, wqT, 0L, Wfold, nullptr, 0L, 512, 512, 512, 2);
  // K[b][c][m] (+knorm2) and Vt[b][m][c], one launch
  gemm_kv<<<dim3(32, 4, 8), blk, 0, stream>>>(wkvB, xT, Kb, Vt, knorm2);
  // q2[b][o][hw] = conv3x3(y; Wfold packed)  (+qnorm2)
  conv3x3<<<dim3(32, 4, 4), blk, 0, stream>>>(Wfold, yT, zeropad, q2, qnorm2);
  attn_g<<<dim3(8, 8, 4), blk, 0, stream>>>(q2, Kb, Gpart);
  softmax_wa<<<dim3(8, 8, 4), blk, 0, stream>>>(Gpart, qnorm2, knorm2, temp, wout, Wa);
  // out[b][o][m] = Wa[b] . Vt[b]^T   -> fp32 d_out
  gemm_bt<<<dim3(32, 4, 4), blk, 0, stream>>>(Wa, S2, Vt, S, nullptr, out, S, 512, 4096, 512, 1);
  (void)in_sizes; (void)n_in; (void)out_size; (void)ws_size;
}

// Round 11
// 286.849 us; speedup vs baseline: 1.0881x; 1.0881x over previous
//
#include <hip/hip_runtime.h>
#include <hip/hip_bf16.h>
#include <math.h>

typedef float f32x4 __attribute__((ext_vector_type(4)));
typedef int   i32x4 __attribute__((ext_vector_type(4)));
typedef short s16x8 __attribute__((ext_vector_type(8)));

#define NB 4
#define NC 512
#define NM 4096
#define NHEADS 8

// async global->LDS, 16B per lane, LDS dest = wave-uniform base + lane*16
#define GLDS16(src, dst) __builtin_amdgcn_global_load_lds( \
    (const __attribute__((address_space(1))) void*)(src),  \
    (__attribute__((address_space(3))) void*)(dst), 16, 0, 0)

// ---------------- merged prep + transpose (disjoint outputs, one launch) ----------------
__global__ __launch_bounds__(256) void prep_tr(
    const float* __restrict__ wdw, const float* __restrict__ wkv,
    const float* __restrict__ wq,
    const float* __restrict__ x, const float* __restrict__ y,
    __hip_bfloat16* __restrict__ Wr, __hip_bfloat16* __restrict__ wkvB,
    __hip_bfloat16* __restrict__ wqT, __hip_bfloat16* __restrict__ zeropad,
    float* __restrict__ norms,
    __hip_bfloat16* __restrict__ xT, __hip_bfloat16* __restrict__ yT)
{
  __shared__ __hip_bfloat16 tile[64][68];
  const int bx = blockIdx.x;
  if (bx < 4113) {
    long idx = (long)bx * 256 + threadIdx.x;
    if (idx < 262144) {                        // 512*512 (o,i) pairs, 9 taps each
      const float* s = wdw + idx * 9;
      #pragma unroll
      for (int r = 0; r < 9; r++)
        Wr[(long)r * 262144 + idx] = __float2bfloat16(s[r]);
    } else if (idx < 786432) {                 // + 1024*512
      long j = idx - 262144;
      wkvB[j] = __float2bfloat16(wkv[j]);
    } else if (idx < 1048576) {                // + 512*512
      long j = idx - 786432;
      int c = (int)(j >> 9), cp = (int)(j & 511);
      wqT[j] = __float2bfloat16(wq[(long)cp * 512 + c]);
    } else if (idx < 1048704) {
      zeropad[idx - 1048576] = __float2bfloat16(0.f);
    } else if (idx < 1052800) {
      norms[idx - 1048704] = 0.f;
    }
  } else {
    const int rem = bx - 4113;
    const int z = rem >> 9;                   // 0..3 x batches, 4..7 y batches
    const int tm = (rem & 63) * 64, tc = ((rem >> 6) & 7) * 64;
    const float* src = ((z < 4) ? x : y) + (long)(z & 3) * ((long)NC * NM);
    __hip_bfloat16* dst = (z < 4 ? xT : yT) + (long)(z & 3) * ((long)NC * NM);
    int tx4 = threadIdx.x & 15, trow = threadIdx.x >> 4;
    #pragma unroll
    for (int p = 0; p < 4; p++) {
      int crow = trow + p * 16;
      f32x4 v = *(const f32x4*)&src[(long)(tc + crow) * NM + tm + tx4 * 4];
      #pragma unroll
      for (int t = 0; t < 4; t++) tile[crow][tx4 * 4 + t] = __float2bfloat16(v[t]);
    }
    __syncthreads();
    #pragma unroll
    for (int p = 0; p < 4; p++) {
      int mrow = trow + p * 16;
      union { ushort4 u4; unsigned short u[4]; } o;
      #pragma unroll
      for (int t = 0; t < 4; t++)
        o.u[t] = *(const unsigned short*)&tile[tx4 * 4 + t][mrow];
      *(ushort4*)&dst[(long)(tm + mrow) * NC + tc + tx4 * 4] = o.u4;
    }
  }
}

// ---------------- generic GEMM: C[M,N] = A[M,K] * B[N,K]^T (row-major bf16, fp32 acc) ----------------
// used only for the final out-projection (outMode 1, f32 out)
__global__ __launch_bounds__(256) void gemm_bt(
    const __hip_bfloat16* __restrict__ Aall, long sA,
    const __hip_bfloat16* __restrict__ Ball, long sB,
    float* __restrict__ Cfall, long sC,
    int N, int Kd)
{
  const __hip_bfloat16* A = Aall + (long)blockIdx.z * sA;
  const __hip_bfloat16* B = Ball + (long)blockIdx.z * sB;
  const int m0 = blockIdx.y * 128, n0 = blockIdx.x * 128;
  __shared__ __hip_bfloat16 As[128 * 32];
  __shared__ __hip_bfloat16 Bs[128 * 32];
  const int tid = threadIdx.x;
  const int wid = tid >> 6, lane = tid & 63;
  const int wm = (wid >> 1) * 64, wn = (wid & 1) * 64;
  const int quad = lane >> 4, l16 = lane & 15;
  const int srow = wid * 32 + (lane >> 2);
  const int scol = (lane & 3) * 8;
  f32x4 acc[4][4] = {};
  for (int k0 = 0; k0 < Kd; k0 += 32) {
    __syncthreads();
    #pragma unroll
    for (int t = 0; t < 2; t++) {
      GLDS16(A + (long)(m0 + srow + t * 16) * Kd + k0 + scol,
             As + (wid * 32 + t * 16) * 32);
      GLDS16(B + (long)(n0 + srow + t * 16) * Kd + k0 + scol,
             Bs + (wid * 32 + t * 16) * 32);
    }
    __builtin_amdgcn_s_waitcnt(0);
    __syncthreads();
    s16x8 bfr[4];
    #pragma unroll
    for (int j = 0; j < 4; j++)
      bfr[j] = *(const s16x8*)(&Bs[(wn + j * 16 + l16) * 32 + quad * 8]);
    #pragma unroll
    for (int i = 0; i < 4; i++) {
      s16x8 af = *(const s16x8*)(&As[(wm + i * 16 + l16) * 32 + quad * 8]);
      #pragma unroll
      for (int j = 0; j < 4; j++)
        acc[i][j] = __builtin_amdgcn_mfma_f32_16x16x32_bf16(af, bfr[j], acc[i][j], 0, 0, 0);
    }
  }
  float* C = Cfall + (long)blockIdx.z * sC;
  #pragma unroll
  for (int i = 0; i < 4; i++)
    #pragma unroll
    for (int j = 0; j < 4; j++) {
      int rbase = m0 + wm + i * 16 + quad * 4;
      int col = n0 + wn + j * 16 + l16;
      #pragma unroll
      for (int r = 0; r < 4; r++)
        C[(long)(rbase + r) * N + col] = acc[i][j][r];
    }
}

// ---------------- merged K/V/Wfold GEMM, one launch ----------------
// grid (36,4,9): z<4 K-mode (x<32 guard): K[b][c][m] bf16 + knorm2;
//               z in 4..7 V-mode (x<32): Vt[b][m][c];
//               z==8: 144 Wfold blocks (f = y*36+x): packed-fragment epilogue.
// All paths share the identical 128x128, K=512, lda=ldb=512 inner loop.
// Rationale: the 144-block Wfold GEMM alone is latency-bound (<=1 block/CU);
// merged, it hides inside gemm_kv's 1024-block occupancy.
__global__ __launch_bounds__(256) void gemm_kvw(
    const __hip_bfloat16* __restrict__ wkvB,
    const __hip_bfloat16* __restrict__ xT,
    const __hip_bfloat16* __restrict__ Wr,
    const __hip_bfloat16* __restrict__ wqT,
    __hip_bfloat16* __restrict__ Kb,
    __hip_bfloat16* __restrict__ Vt,
    __hip_bfloat16* __restrict__ Wfold,
    float* __restrict__ knorm2)
{
  const int z = blockIdx.z;
  const long S = (long)NM * NC;
  const long S2 = (long)512 * 512;
  const int b = z & 3;
  const __hip_bfloat16 *A, *B;
  __hip_bfloat16* C = nullptr;
  int m0, n0, N, mode, rt = 0;
  if (z == 8) {
    const int f = blockIdx.y * 36 + blockIdx.x;   // 0..143
    rt = f >> 4;
    const int q = f & 15;
    m0 = (q >> 2) * 128; n0 = (q & 3) * 128;
    A = Wr + (long)rt * S2; B = wqT; N = 512; mode = 2;
  } else if (z < 4) {
    if (blockIdx.x >= 32) return;
    A = wkvB; B = xT + b * S; C = Kb + b * S;
    m0 = blockIdx.y * 128; n0 = blockIdx.x * 128; N = NM; mode = 0;
  } else {
    if (blockIdx.x >= 32) return;
    A = xT + b * S; B = wkvB + 262144; C = Vt + b * S;
    m0 = blockIdx.x * 128; n0 = blockIdx.y * 128; N = NC; mode = 1;
  }
  __shared__ __hip_bfloat16 As[128 * 32];
  __shared__ __hip_bfloat16 Bs[128 * 32];
  const int tid = threadIdx.x;
  const int wid = tid >> 6, lane = tid & 63;
  const int wm = (wid >> 1) * 64, wn = (wid & 1) * 64;
  const int quad = lane >> 4, l16 = lane & 15;
  const int srow = wid * 32 + (lane >> 2);
  const int scol = (lane & 3) * 8;
  f32x4 acc[4][4] = {};
  for (int k0 = 0; k0 < NC; k0 += 32) {
    __syncthreads();
    #pragma unroll
    for (int t = 0; t < 2; t++) {
      GLDS16(A + (long)(m0 + srow + t * 16) * NC + k0 + scol,
             As + (wid * 32 + t * 16) * 32);
      GLDS16(B + (long)(n0 + srow + t * 16) * NC + k0 + scol,
             Bs + (wid * 32 + t * 16) * 32);
    }
    __builtin_amdgcn_s_waitcnt(0);
    __syncthreads();
    s16x8 bfr[4];
    #pragma unroll
    for (int j = 0; j < 4; j++)
      bfr[j] = *(const s16x8*)(&Bs[(wn + j * 16 + l16) * 32 + quad * 8]);
    #pragma unroll
    for (int i = 0; i < 4; i++) {
      s16x8 af = *(const s16x8*)(&As[(wm + i * 16 + l16) * 32 + quad * 8]);
      #pragma unroll
      for (int j = 0; j < 4; j++)
        acc[i][j] = __builtin_amdgcn_mfma_f32_16x16x32_bf16(af, bfr[j], acc[i][j], 0, 0, 0);
    }
  }
  if (mode == 2) {
    #pragma unroll
    for (int i = 0; i < 4; i++)
      #pragma unroll
      for (int j = 0; j < 4; j++) {
        int obase = m0 + wm + i * 16 + quad * 4;
        int col = n0 + wn + j * 16 + l16;
        #pragma unroll
        for (int r = 0; r < 4; r++) {
          int o = obase + r;
          long idx = ((((long)(rt * 32 + (o >> 4)) * 16 + (col >> 5)) << 9)
                      + ((col >> 3) & 3) * 128 + (o & 15) * 8 + (col & 7));
          Wfold[idx] = __float2bfloat16(acc[i][j][r]);
        }
      }
    return;
  }
  #pragma unroll
  for (int i = 0; i < 4; i++)
    #pragma unroll
    for (int j = 0; j < 4; j++) {
      int rbase = m0 + wm + i * 16 + quad * 4;
      int col = n0 + wn + j * 16 + l16;
      #pragma unroll
      for (int r = 0; r < 4; r++)
        C[(long)(rbase + r) * N + col] = __float2bfloat16(acc[i][j][r]);
    }
  if (mode == 0) {   // knorm2[b*512 + c] += sum over this tile's m-cols of K[c,m]^2
    #pragma unroll
    for (int i = 0; i < 4; i++) {
      int rbase = m0 + wm + i * 16 + quad * 4;
      #pragma unroll
      for (int r = 0; r < 4; r++) {
        float s = 0.f;
        #pragma unroll
        for (int j = 0; j < 4; j++) s += acc[i][j][r] * acc[i][j][r];
        s += __shfl_xor(s, 1); s += __shfl_xor(s, 2);
        s += __shfl_xor(s, 4); s += __shfl_xor(s, 8);
        if (l16 == 0) atomicAdd(&knorm2[b * 512 + rbase + r], s);
      }
    }
  }
}

// ---------------- 3x3 conv as implicit GEMM (w_q folded), + qnorm2 partials ----------------
// v11 = byte-exact v9/v4 conv (proven best 81.5µs, twice): A staged via GLDS16 packed
//      layout, dbuf A+B, 3 drains/icb, natural block mapping, uniform-select t loop.
//      v10's per-tap counted-vmcnt ring (113µs) reverted: 144 barriers > 48 drains.
//      Conv structure declared plateaued at 81.5µs / 40% MfmaUtil.
__global__ __launch_bounds__(256) void conv3x3(
    const __hip_bfloat16* __restrict__ Wp,   // packed [9][32][16][64][8] fragments
    const __hip_bfloat16* __restrict__ yT,   // [b][4096][512]
    const __hip_bfloat16* __restrict__ zeropad,
    __hip_bfloat16* __restrict__ q2,         // [b][512][4096]
    float* __restrict__ qnorm2)
{
  const int b = blockIdx.z;
  const int n0 = blockIdx.x * 128;   // hw tile (2 image rows)
  const int m0 = blockIdx.y * 128;   // o tile
  __shared__ __hip_bfloat16 As2[2][24 * 512];   // 2 x 24KB: 24 packed A frags (3 taps x 8 mb)
  __shared__ __hip_bfloat16 Bs2[2][256 * 32];   // 2 x 16KB: 4 image rows (incl halo) x 32 ic
  const int tid = threadIdx.x;
  const int wid = tid >> 6, lane = tid & 63;
  const int wm = (wid >> 1) * 64, wn = (wid & 1) * 64;
  const int quad = lane >> 4, l16 = lane & 15;
  const int lrow = lane >> 2;
  const int h0 = n0 >> 6;
  const int mb0b = m0 >> 4;
  const int mwl = wm >> 4;            // 0 or 4: this wave's mb offset within block
  const __hip_bfloat16* yb = yT + (long)b * NM * NC;
  f32x4 acc[4][4] = {};
  const s16x8 zero8 = {0, 0, 0, 0, 0, 0, 0, 0};

  // B staging source column swizzle: slot' = (lane&3) ^ ((lds_row>>1)&3)
  const int sq = ((lane & 3) ^ ((lane >> 3) & 3)) * 8;

  // B LDS read addrs (dy=-1 base; +g*2048 per dy) and validity bits (verified v2-v10).
  int addr0[3][4];
  unsigned vbits = 0;
  #pragma unroll
  for (int t = 0; t < 3; t++) {
    #pragma unroll
    for (int j = 0; j < 4; j++) {
      int nl = wn + j * 16 + l16;
      int wq_ = nl & 63, hr = nl >> 6;
      int wp = wq_ + t - 1;                  // dx = t-1
      unsigned v = ((unsigned)wp) < 64u;
      int p = v ? (hr * 64 + wp) : 0;        // dy=-1: row hr
      addr0[t][j] = p * 32 + ((quad ^ ((p >> 1) & 3)) * 8);
      vbits |= v << (t * 4 + j);
    }
  }

  // prologue: stage A(phase g=0, icb=0) -> As2[0], B(icb=0) -> Bs2[0]
  #pragma unroll
  for (int k = 0; k < 6; k++) {
    int f = wid * 6 + k;
    GLDS16(Wp + (((long)(((f >> 3)) * 32 + mb0b + (f & 7)) * 16 + 0) << 9) + lane * 8,
           &As2[0][f * 512]);
  }
  #pragma unroll
  for (int t = 0; t < 4; t++) {
    int pr = wid * 64 + t * 16 + lrow;
    int hw = (h0 - 1) * 64 + pr;
    const __hip_bfloat16* src = (((unsigned)hw) < (unsigned)NM)
        ? (yb + (long)hw * NC + sq) : zeropad;
    GLDS16(src, &Bs2[0][(wid * 64 + t * 16) * 32]);
  }
  __builtin_amdgcn_s_waitcnt(0);
  __syncthreads();

  for (int icb = 0; icb < 16; icb++) {
    const __hip_bfloat16* Bcur = &Bs2[icb & 1][0];
    #pragma unroll
    for (int g = 0; g < 3; g++) {
      const int cb = (icb ^ g) & 1;            // current A buffer parity
      const __hip_bfloat16* Acur = &As2[cb][0];
      __hip_bfloat16* Anxt = (__hip_bfloat16*)&As2[cb ^ 1][0];
      // 1) issue next phase's A stage (into the buffer last read 2 phases ago; barrier-safe)
      if (icb < 15 || g < 2) {
        const int gn = (g == 2) ? 0 : g + 1;
        const int icbn = (g == 2) ? icb + 1 : icb;
        #pragma unroll
        for (int k = 0; k < 6; k++) {
          int f = wid * 6 + k;
          GLDS16(Wp + (((long)((gn * 3 + (f >> 3)) * 32 + mb0b + (f & 7)) * 16 + icbn) << 9) + lane * 8,
                 Anxt + f * 512);
        }
      }
      // 2) issue next icb's B stage during the middle phase
      if (g == 1 && icb < 15) {
        __hip_bfloat16* Bnxt = (__hip_bfloat16*)&Bs2[(icb & 1) ^ 1][0];
        #pragma unroll
        for (int t = 0; t < 4; t++) {
          int pr = wid * 64 + t * 16 + lrow;
          int hw = (h0 - 1) * 64 + pr;
          const __hip_bfloat16* src = (((unsigned)hw) < (unsigned)NM)
              ? (yb + (long)hw * NC + (icb + 1) * 32 + sq) : zeropad;
          GLDS16(src, Bnxt + (wid * 64 + t * 16) * 32);
        }
      }
      // 3) compute: 3 taps x 16 MFMA from current buffers
      #pragma unroll
      for (int t = 0; t < 3; t++) {
        s16x8 bfr[4];
        #pragma unroll
        for (int j = 0; j < 4; j++) {
          s16x8 tt = *(const s16x8*)(&Bcur[addr0[t][j] + g * 2048]);
          bfr[j] = ((vbits >> (t * 4 + j)) & 1u) ? tt : zero8;
        }
        #pragma unroll
        for (int i = 0; i < 4; i++) {
          s16x8 af = *(const s16x8*)(&Acur[(t * 8 + mwl + i) * 512 + lane * 8]);
          #pragma unroll
          for (int j = 0; j < 4; j++)
            acc[i][j] = __builtin_amdgcn_mfma_f32_16x16x32_bf16(af, bfr[j], acc[i][j], 0, 0, 0);
        }
      }
      // 4) drain (loads had the whole compute to land) + barrier
      __builtin_amdgcn_s_waitcnt(0);
      __syncthreads();
    }
  }

  __hip_bfloat16* Cb = q2 + (long)b * NC * NM;
  #pragma unroll
  for (int i = 0; i < 4; i++)
    #pragma unroll
    for (int j = 0; j < 4; j++) {
      int rbase = m0 + wm + i * 16 + quad * 4;
      int col = n0 + wn + j * 16 + l16;
      #pragma unroll
      for (int r = 0; r < 4; r++)
        Cb[(long)(rbase + r) * NM + col] = __float2bfloat16(acc[i][j][r]);
    }
  // qnorm2[b*512 + o] += sum over this tile's hw-cols of q2[o,hw]^2
  #pragma unroll
  for (int i = 0; i < 4; i++) {
    int rbase = m0 + wm + i * 16 + quad * 4;
    #pragma unroll
    for (int r = 0; r < 4; r++) {
      float s = 0.f;
      #pragma unroll
      for (int j = 0; j < 4; j++) s += acc[i][j][r] * acc[i][j][r];
      s += __shfl_xor(s, 1); s += __shfl_xor(s, 2);
      s += __shfl_xor(s, 4); s += __shfl_xor(s, 8);
      if (l16 == 0) atomicAdd(&qnorm2[b * 512 + rbase + r], s);
    }
  }
}

// ---------------- attention logits partial: Gpart[b,h,mc][c][d] over m-chunk ----------------
__global__ __launch_bounds__(256) void attn_g(
    const __hip_bfloat16* __restrict__ q2, const __hip_bfloat16* __restrict__ Kb,
    float* __restrict__ Gpart)
{
  const int mc = blockIdx.x, h = blockIdx.y, b = blockIdx.z;
  const __hip_bfloat16* qrow = q2 + ((long)b * NC + h * 64) * NM + mc * 512;
  const __hip_bfloat16* krow = Kb + ((long)b * NC + h * 64) * NM + mc * 512;
  __shared__ __hip_bfloat16 Qs[64 * 40];
  __shared__ __hip_bfloat16 Ks[64 * 40];
  const int tid = threadIdx.x;
  const int wid = tid >> 6, lane = tid & 63;
  const int wc = (wid >> 1) * 32, wd = (wid & 1) * 32;
  const int quad = lane >> 4, l16 = lane & 15;
  const int srow = tid >> 2, scol = (tid & 3) * 8;
  f32x4 acc[2][2] = {};
  for (int k0 = 0; k0 < 512; k0 += 32) {
    __syncthreads();
    *(i32x4*)(&Qs[srow * 40 + scol]) = *(const i32x4*)(&qrow[(long)srow * NM + k0 + scol]);
    *(i32x4*)(&Ks[srow * 40 + scol]) = *(const i32x4*)(&krow[(long)srow * NM + k0 + scol]);
    __syncthreads();
    s16x8 bfr[2];
    #pragma unroll
    for (int j = 0; j < 2; j++)
      bfr[j] = *(const s16x8*)(&Ks[(wd + j * 16 + l16) * 40 + quad * 8]);
    #pragma unroll
    for (int i = 0; i < 2; i++) {
      s16x8 af = *(const s16x8*)(&Qs[(wc + i * 16 + l16) * 40 + quad * 8]);
      #pragma unroll
      for (int j = 0; j < 2; j++)
        acc[i][j] = __builtin_amdgcn_mfma_f32_16x16x32_bf16(af, bfr[j], acc[i][j], 0, 0, 0);
    }
  }
  float* gp = Gpart + ((long)((b * 8 + h) * 8 + mc)) * 4096;
  #pragma unroll
  for (int i = 0; i < 2; i++)
    #pragma unroll
    for (int j = 0; j < 2; j++)
      #pragma unroll
      for (int r = 0; r < 4; r++)
        gp[(wc + i * 16 + quad * 4 + r) * 64 + wd + j * 16 + l16] = acc[i][j][r];
}

// ---------------- fused: sum partials -> normalize -> softmax -> Wa = (wout chunk) . attn ----------------
__global__ __launch_bounds__(256) void softmax_wa(
    const float* __restrict__ Gpart, const float* __restrict__ qnorm2,
    const float* __restrict__ knorm2, const float* __restrict__ temp,
    const float* __restrict__ wout, __hip_bfloat16* __restrict__ Wa)
{
  const int oc = blockIdx.x, h = blockIdx.y, b = blockIdx.z;
  __shared__ float G[64][64];
  __shared__ float Wt[64][65];
  const int tid = threadIdx.x;
  const float tv = temp[h];
  for (int e = tid; e < 4096; e += 256) {
    float s = 0.f;
    #pragma unroll
    for (int p = 0; p < 8; p++)
      s += Gpart[((long)((b * 8 + h) * 8 + p)) * 4096 + e];
    int c = e >> 6, d = e & 63;
    float qn = fmaxf(sqrtf(qnorm2[b * 512 + h * 64 + c]), 1e-12f);
    float kn = fmaxf(sqrtf(knorm2[b * 512 + h * 64 + d]), 1e-12f);
    G[c][d] = s * tv / (qn * kn);
    Wt[c][d] = wout[(long)(oc * 64 + c) * 512 + h * 64 + d];
  }
  __syncthreads();
  int row = tid >> 2, s4 = tid & 3;
  float mx = -1e30f;
  for (int d = s4; d < 64; d += 4) mx = fmaxf(mx, G[row][d]);
  mx = fmaxf(mx, __shfl_xor(mx, 1));
  mx = fmaxf(mx, __shfl_xor(mx, 2));
  float sum = 0.f;
  for (int d = s4; d < 64; d += 4) { float e = __expf(G[row][d] - mx); G[row][d] = e; sum += e; }
  sum += __shfl_xor(sum, 1);
  sum += __shfl_xor(sum, 2);
  float inv = 1.f / sum;
  for (int d = s4; d < 64; d += 4) G[row][d] *= inv;
  __syncthreads();
  int d = tid & 63, og = tid >> 6;
  #pragma unroll
  for (int k2 = 0; k2 < 16; k2++) {
    int o = og * 16 + k2;
    float s = 0.f;
    #pragma unroll 8
    for (int c = 0; c < 64; c++) s += Wt[o][c] * G[c][d];
    Wa[((long)b * 512 + oc * 64 + o) * 512 + h * 64 + d] = __float2bfloat16(s);
  }
}

extern "C" void kernel_launch(void* const* d_in, const int* in_sizes, int n_in,
                              void* d_out, int out_size, void* d_ws, size_t ws_size,
                              hipStream_t stream) {
  const float* x    = (const float*)d_in[0];
  const float* y    = (const float*)d_in[1];
  const float* temp = (const float*)d_in[2];
  const float* wkv  = (const float*)d_in[3];
  const float* wq   = (const float*)d_in[4];
  const float* wdw  = (const float*)d_in[5];
  const float* wout = (const float*)d_in[6];
  float* out = (float*)d_out;     // fp32 output

  char* ws = (char*)d_ws;
  const long TEN = 16777216;  // one (4,512,4096) bf16 tensor, bytes
  __hip_bfloat16* xT  = (__hip_bfloat16*)(ws);               // reused as q2 after kv GEMM
  __hip_bfloat16* q2  = xT;
  __hip_bfloat16* yT  = (__hip_bfloat16*)(ws + TEN);         // reused after conv:
  float* Gpart        = (float*)(ws + TEN);                  //   4 MB
  __hip_bfloat16* Wa  = (__hip_bfloat16*)(ws + TEN + 4718592);   // 2 MB
  __hip_bfloat16* Kb  = (__hip_bfloat16*)(ws + 2 * TEN);
  __hip_bfloat16* Vt  = (__hip_bfloat16*)(ws + 3 * TEN);
  __hip_bfloat16* Wfold = (__hip_bfloat16*)(ws + 4 * TEN);               // 4.72 MB (packed)
  __hip_bfloat16* Wr    = (__hip_bfloat16*)(ws + 4 * TEN + 4718592);     // 4.72 MB
  __hip_bfloat16* wkvB  = (__hip_bfloat16*)(ws + 4 * TEN + 9437184);     // 1 MB
  __hip_bfloat16* wqT   = (__hip_bfloat16*)(ws + 4 * TEN + 10485760);    // 512 KB
  __hip_bfloat16* zeropad = (__hip_bfloat16*)(ws + 4 * TEN + 11010048);  // 256 B
  float* norms          = (float*)(ws + 4 * TEN + 11010304);             // 16 KB
  float* knorm2 = norms;
  float* qnorm2 = norms + 2048;

  const long S = (long)4096 * 512;
  const long S2 = (long)512 * 512;
  dim3 blk(256);

  // merged prep + transpose (4113 prep blocks + 4096 transpose blocks)
  prep_tr<<<dim3(8209), blk, 0, stream>>>(wdw, wkv, wq, x, y,
                                          Wr, wkvB, wqT, zeropad, norms, xT, yT);
  // merged K/V GEMM + Wfold packed-fragment GEMM (Wfold hides in kv occupancy)
  gemm_kvw<<<dim3(36, 4, 9), blk, 0, stream>>>(wkvB, xT, Wr, wqT, Kb, Vt, Wfold, knorm2);
  // q2[b][o][hw] = conv3x3(y; Wfold packed)  (+qnorm2)
  conv3x3<<<dim3(32, 4, 4), blk, 0, stream>>>(Wfold, yT, zeropad, q2, qnorm2);
  attn_g<<<dim3(8, 8, 4), blk, 0, stream>>>(q2, Kb, Gpart);
  softmax_wa<<<dim3(8, 8, 4), blk, 0, stream>>>(Gpart, qnorm2, knorm2, temp, wout, Wa);
  // out[b][o][m] = Wa[b] . Vt[b]^T   -> fp32 d_out
  gemm_bt<<<dim3(32, 4, 4), blk, 0, stream>>>(Wa, S2, Vt, S, out, S, 4096, 512);
  (void)in_sizes; (void)n_in; (void)out_size; (void)ws_size;
}